// Round 3
// baseline (2725.940 us; speedup 1.0000x reference)
//
#include <hip/hip_runtime.h>

#define EPS 1e-5f

// fast accurate-enough tanh: 1 v_exp + 1 v_rcp, abs err ~1e-7, no overflow
__device__ __forceinline__ float tanh_fast(float x) {
  float ax = fabsf(x);
  float e  = __expf(-2.0f * ax);
  float r  = (1.0f - e) * __builtin_amdgcn_rcpf(1.0f + e);
  return copysignf(r, x);
}

// ---------------------------------------------------------------------------
// Kernel A: h0 = tanh(groupnorm(x @ W_in + b_in) * gamma1 + beta1)
// block = 256 threads = 64 rows x 4 K-quads; grid = 1024 blocks.
// launch_bounds(256,1): round-1's (256,4) clamped to 64 VGPR and spilled
// acc[64] to scratch (1.58 GB scratch writes, VALUBusy 3%). Cap 512 now.
// ---------------------------------------------------------------------------
__global__ __launch_bounds__(256, 1) void kA(
    const float* __restrict__ x, const float* __restrict__ Win,
    const float* __restrict__ bin, const float* __restrict__ g1,
    const float* __restrict__ be1, float* __restrict__ h0) {
  const int tid = threadIdx.x;
  const int r = tid >> 2, q = tid & 3;            // row-in-block, k-quad
  const size_t row = (size_t)blockIdx.x * 64 + r;
  const float4* __restrict__ x4 = (const float4*)x + row * (784 / 4) + q * 49;
  const float4* __restrict__ W4 = (const float4*)Win;   // [784][16] float4

  float acc[64];
#pragma unroll
  for (int j = 0; j < 64; ++j) acc[j] = 0.f;

  const int kbase = q * 196;
#pragma unroll 2
  for (int i4 = 0; i4 < 49; ++i4) {
    float4 xv = x4[i4];
    const float4* __restrict__ wrow = W4 + (size_t)(kbase + i4 * 4) * 16;
#pragma unroll
    for (int i = 0; i < 4; ++i) {
      float xs = (i == 0) ? xv.x : (i == 1) ? xv.y : (i == 2) ? xv.z : xv.w;
      const float4* __restrict__ wr = wrow + i * 16;
#pragma unroll
      for (int j4 = 0; j4 < 16; ++j4) {
        float4 w = wr[j4];
        acc[4 * j4 + 0] = fmaf(xs, w.x, acc[4 * j4 + 0]);
        acc[4 * j4 + 1] = fmaf(xs, w.y, acc[4 * j4 + 1]);
        acc[4 * j4 + 2] = fmaf(xs, w.z, acc[4 * j4 + 2]);
        acc[4 * j4 + 3] = fmaf(xs, w.w, acc[4 * j4 + 3]);
      }
    }
  }

  // reduce across the 4 quad lanes (masks 1,2 stay inside the quad)
#pragma unroll
  for (int j = 0; j < 64; ++j) {
    acc[j] += __shfl_xor(acc[j], 1, 64);
    acc[j] += __shfl_xor(acc[j], 2, 64);
  }

  // each lane keeps its 16 channels (2 groupnorm groups). q is runtime ->
  // exec-masked static extract (rule #20: no runtime reg indexing).
  float v[16];
  if (q == 0) {
#pragma unroll
    for (int j = 0; j < 16; ++j) v[j] = acc[j];
  } else if (q == 1) {
#pragma unroll
    for (int j = 0; j < 16; ++j) v[j] = acc[16 + j];
  } else if (q == 2) {
#pragma unroll
    for (int j = 0; j < 16; ++j) v[j] = acc[32 + j];
  } else {
#pragma unroll
    for (int j = 0; j < 16; ++j) v[j] = acc[48 + j];
  }
  const int c0 = q * 16;
#pragma unroll
  for (int j = 0; j < 16; ++j) v[j] += bin[c0 + j];

  float o[16];
#pragma unroll
  for (int g = 0; g < 2; ++g) {
    float mu = 0.f;
#pragma unroll
    for (int i = 0; i < 8; ++i) mu += v[g * 8 + i];
    mu *= 0.125f;
    float var = 0.f;
#pragma unroll
    for (int i = 0; i < 8; ++i) { float d = v[g * 8 + i] - mu; var = fmaf(d, d, var); }
    var *= 0.125f;
    float rs = rsqrtf(var + EPS);
#pragma unroll
    for (int i = 0; i < 8; ++i) {
      float y = (v[g * 8 + i] - mu) * rs * g1[c0 + g * 8 + i] + be1[c0 + g * 8 + i];
      o[g * 8 + i] = tanh_fast(y);
    }
  }

  float4* dst = (float4*)(h0 + row * 64 + c0);
#pragma unroll
  for (int i = 0; i < 4; ++i)
    dst[i] = make_float4(o[4 * i], o[4 * i + 1], o[4 * i + 2], o[4 * i + 3]);
}

// ---------------------------------------------------------------------------
// Kernel B (RESTRUCTURED): 1 row per lane, all 64 channels per lane.
// Weight addresses are wave-uniform -> compiler emits s_load (SGPR weights,
// scalar pipe/K$), FMAs are v_fmac v,s,v. Round-1 kB spent 9 LDS ops per
// 32 FMAs on LDS-broadcast weights -> LDS-issue-bound (974us vs 273us FMA
// floor). Now LDS holds only the per-lane-PRIVATE arg vector (dynamic k
// index must not hit registers -> rule #20). No cross-thread data -> no
// barriers. stride 68 floats: 16B-aligned for b128, 4-bank rotation/lane.
// Occupancy is grid-limited (65536 rows / 64 = 1024 waves = 1 wave/SIMD),
// so VGPRs are free up to 512: h[64]+s[64]+kv[64] ~ 215 VGPR, no spill.
// ---------------------------------------------------------------------------
__global__ __launch_bounds__(256, 1) void kB(
    const float* __restrict__ h0,
    const float* __restrict__ W1, const float* __restrict__ b1,
    const float* __restrict__ W2, const float* __restrict__ b2,
    const float* __restrict__ g2, const float* __restrict__ be2,
    const float* __restrict__ Wout, const float* __restrict__ bout,
    const int* __restrict__ nsp, float* __restrict__ out) {
  __shared__ float u[256 * 68];                 // 69,632 B
  const int tid = threadIdx.x;
  float* __restrict__ ur = u + tid * 68;
  float4* __restrict__ ur4 = (float4*)ur;
  const size_t row = (size_t)blockIdx.x * 256 + tid;

  float h[64], s[64], kv[64];
  {
    const float4* hsrc = (const float4*)(h0 + row * 64);
#pragma unroll
    for (int i = 0; i < 16; ++i) {
      float4 t = hsrc[i];
      h[4 * i + 0] = t.x; h[4 * i + 1] = t.y;
      h[4 * i + 2] = t.z; h[4 * i + 3] = t.w;
    }
  }

  const int ns = *nsp;
  const float dt  = 1.0f / (float)ns;
  const float dt6 = dt * (1.0f / 6.0f);
  const float dt3 = dt * (1.0f / 3.0f);
  const float dth = dt * 0.5f;

#pragma unroll 1
  for (int step = 0; step < ns; ++step) {
    // arg <- h (to private LDS row); s <- h
#pragma unroll
    for (int i = 0; i < 16; ++i) {
      ur4[i] = make_float4(h[4 * i], h[4 * i + 1], h[4 * i + 2], h[4 * i + 3]);
      s[4 * i + 0] = h[4 * i + 0]; s[4 * i + 1] = h[4 * i + 1];
      s[4 * i + 2] = h[4 * i + 2]; s[4 * i + 3] = h[4 * i + 3];
    }

#pragma unroll 1
    for (int e = 0; e < 4; ++e) {
      // ---- z = W1^T arg + b1 (weights via wave-uniform s_load) ----
#pragma unroll
      for (int j = 0; j < 64; ++j) kv[j] = b1[j];
#pragma unroll 2
      for (int k4 = 0; k4 < 16; ++k4) {
        float4 in4 = ur4[k4];
        const float* __restrict__ wbase = W1 + k4 * 256;
#pragma unroll
        for (int kk = 0; kk < 4; ++kk) {
          float in = (kk == 0) ? in4.x : (kk == 1) ? in4.y : (kk == 2) ? in4.z : in4.w;
          const float* __restrict__ wr = wbase + kk * 64;
#pragma unroll
          for (int j = 0; j < 64; ++j) kv[j] = fmaf(in, wr[j], kv[j]);
        }
      }
      // ---- t = tanh(z) -> private LDS row ----
#pragma unroll
      for (int i = 0; i < 16; ++i)
        ur4[i] = make_float4(tanh_fast(kv[4 * i + 0]), tanh_fast(kv[4 * i + 1]),
                             tanh_fast(kv[4 * i + 2]), tanh_fast(kv[4 * i + 3]));
      // ---- kv = W2^T t + b2 ----
#pragma unroll
      for (int j = 0; j < 64; ++j) kv[j] = b2[j];
#pragma unroll 2
      for (int k4 = 0; k4 < 16; ++k4) {
        float4 in4 = ur4[k4];
        const float* __restrict__ wbase = W2 + k4 * 256;
#pragma unroll
        for (int kk = 0; kk < 4; ++kk) {
          float in = (kk == 0) ? in4.x : (kk == 1) ? in4.y : (kk == 2) ? in4.z : in4.w;
          const float* __restrict__ wr = wbase + kk * 64;
#pragma unroll
          for (int j = 0; j < 64; ++j) kv[j] = fmaf(in, wr[j], kv[j]);
        }
      }
      // ---- RK4 update ----
      if (e < 3) {
        const float cs = (e == 0) ? dt6 : dt3;
        const float ca = (e == 2) ? dt : dth;
#pragma unroll
        for (int i = 0; i < 16; ++i) {
          float a0 = fmaf(ca, kv[4 * i + 0], h[4 * i + 0]);
          float a1 = fmaf(ca, kv[4 * i + 1], h[4 * i + 1]);
          float a2 = fmaf(ca, kv[4 * i + 2], h[4 * i + 2]);
          float a3 = fmaf(ca, kv[4 * i + 3], h[4 * i + 3]);
          s[4 * i + 0] = fmaf(cs, kv[4 * i + 0], s[4 * i + 0]);
          s[4 * i + 1] = fmaf(cs, kv[4 * i + 1], s[4 * i + 1]);
          s[4 * i + 2] = fmaf(cs, kv[4 * i + 2], s[4 * i + 2]);
          s[4 * i + 3] = fmaf(cs, kv[4 * i + 3], s[4 * i + 3]);
          ur4[i] = make_float4(a0, a1, a2, a3);   // next arg
        }
      } else {
#pragma unroll
        for (int j = 0; j < 64; ++j) h[j] = fmaf(dt6, kv[j], s[j]);
      }
    }
  }

  // ---- groupnorm2: 8 groups of 8, fully per-lane ----
  float g[64];
#pragma unroll
  for (int grp = 0; grp < 8; ++grp) {
    float mu = 0.f;
#pragma unroll
    for (int i = 0; i < 8; ++i) mu += h[grp * 8 + i];
    mu *= 0.125f;
    float var = 0.f;
#pragma unroll
    for (int i = 0; i < 8; ++i) { float d = h[grp * 8 + i] - mu; var = fmaf(d, d, var); }
    var *= 0.125f;
    float rs = rsqrtf(var + EPS);
#pragma unroll
    for (int i = 0; i < 8; ++i) {
      int c = grp * 8 + i;
      g[c] = (h[c] - mu) * rs * g2[c] + be2[c];   // g2/be2: uniform s_loads
    }
  }

  // ---- logits + log_softmax (Wout/bout uniform s_loads) ----
  float lg[10];
#pragma unroll
  for (int c = 0; c < 10; ++c) lg[c] = bout[c];
#pragma unroll
  for (int j = 0; j < 64; ++j) {
    float gv = g[j];
    const float* __restrict__ wr = Wout + j * 10;
#pragma unroll
    for (int c = 0; c < 10; ++c) lg[c] = fmaf(gv, wr[c], lg[c]);
  }

  float m = lg[0];
#pragma unroll
  for (int c = 1; c < 10; ++c) m = fmaxf(m, lg[c]);
  float sum = 0.f;
#pragma unroll
  for (int c = 0; c < 10; ++c) sum += __expf(lg[c] - m);
  float lse = m + __logf(sum);

  float* op = out + row * 10;
#pragma unroll
  for (int c = 0; c < 10; ++c) op[c] = lg[c] - lse;
}

extern "C" void kernel_launch(void* const* d_in, const int* in_sizes, int n_in,
                              void* d_out, int out_size, void* d_ws, size_t ws_size,
                              hipStream_t stream) {
  const float* x    = (const float*)d_in[0];
  const float* Win  = (const float*)d_in[1];
  const float* bin  = (const float*)d_in[2];
  const float* g1   = (const float*)d_in[3];
  const float* be1  = (const float*)d_in[4];
  const float* W1   = (const float*)d_in[5];
  const float* b1   = (const float*)d_in[6];
  const float* W2   = (const float*)d_in[7];
  const float* b2   = (const float*)d_in[8];
  const float* g2   = (const float*)d_in[9];
  const float* be2  = (const float*)d_in[10];
  const float* Wout = (const float*)d_in[11];
  const float* bout = (const float*)d_in[12];
  const int*   nsp  = (const int*)d_in[13];
  float* out = (float*)d_out;
  float* h0  = (float*)d_ws;   // 65536*64*4 = 16.78 MB scratch

  kA<<<1024, 256, 0, stream>>>(x, Win, bin, g1, be1, h0);
  kB<<<256, 256, 0, stream>>>(h0, W1, b1, W2, b2, g2, be2, Wout, bout, nsp, out);
}

// Round 5
// 655.484 us; speedup vs baseline: 4.1587x; 4.1587x over previous
//
#include <hip/hip_runtime.h>

#define EPS 1e-5f

typedef __attribute__((ext_vector_type(8))) short short8;   // 8 bf16 = 4 VGPR
typedef __attribute__((ext_vector_type(4))) float f32x4;    // MFMA C/D
typedef __attribute__((ext_vector_type(2))) unsigned int uint2v;

// fast accurate-enough tanh: 1 v_exp + 1 v_rcp, abs err ~1e-7, no overflow
__device__ __forceinline__ float tanh_fast(float x) {
  float ax = fabsf(x);
  float e  = __expf(-2.0f * ax);
  float r  = (1.0f - e) * __builtin_amdgcn_rcpf(1.0f + e);
  return copysignf(r, x);
}

// split f32 -> bf16 hi + bf16 lo (bit-trick, round-to-nearest-ish).
// 3-term MFMA (WhUh + WhUl + WlUh) gives ~2^-17 rel err per product.
__device__ __forceinline__ void split_bf16(float v, unsigned& hb, unsigned& lb) {
  unsigned u = __float_as_uint(v);
  hb = (u + 0x8000u) & 0xffff0000u;
  float lf = v - __uint_as_float(hb);
  lb = (__float_as_uint(lf) + 0x8000u) & 0xffff0000u;
}

__device__ __forceinline__ f32x4 MF(short8 a, short8 b, f32x4 c) {
  return __builtin_amdgcn_mfma_f32_16x16x32_bf16(a, b, c, 0, 0, 0);
}

// ---------------------------------------------------------------------------
// Kernel A: h0 = tanh(groupnorm(x @ W_in + b_in) * g1 + be1)
// Round-3 counters: VALUBusy 3.3%, HBM 1.3% -> transaction-bound: per-wave
// x-loads hit 64 distinct lines (784B lane stride) ~= 3.2M line-gathers/CU
// ~= 1333us. Fix: LDS-stage x AND W coalesced; compute from LDS.
// 7 K-chunks of 112. xs pad 116, ws pad 68 (16B-align, ~2-way banks).
// LDS 60,160B -> 2 blocks/CU (8 waves/CU). VALU floor 42us.
// ---------------------------------------------------------------------------
__global__ __launch_bounds__(256, 2) void kA(
    const float* __restrict__ x, const float* __restrict__ Win,
    const float* __restrict__ bin, const float* __restrict__ g1,
    const float* __restrict__ be1, float* __restrict__ h0) {
  __shared__ __align__(16) float xs[64 * 116];
  __shared__ __align__(16) float ws[112 * 68];
  const int tid = threadIdx.x;
  const int r = tid >> 2, q = tid & 3;
  const size_t row0 = (size_t)blockIdx.x * 64;

  float acc[64];
#pragma unroll
  for (int j = 0; j < 64; ++j) acc[j] = 0.f;

  const float4* __restrict__ xg = (const float4*)x;    // [B][196] f4
  const float4* __restrict__ wg = (const float4*)Win;  // [784][16] f4

#pragma unroll 1
  for (int kc = 0; kc < 7; ++kc) {
    __syncthreads();   // protect previous chunk's LDS reads
    // stage x chunk [64 rows][112 cols]: 1792 float4 = 7*256 exact, coalesced
#pragma unroll 1
    for (int it = 0; it < 7; ++it) {
      int idx = it * 256 + tid;
      int rr = idx / 28, c4 = idx % 28;
      float4 v = xg[(row0 + rr) * 196 + kc * 28 + c4];
      *(float4*)&xs[rr * 116 + c4 * 4] = v;
    }
    // stage W chunk [112 k][64 ch]: 1792 float4, fully coalesced
#pragma unroll 1
    for (int it = 0; it < 7; ++it) {
      int idx = it * 256 + tid;
      int kr = idx >> 4, j4 = idx & 15;
      float4 v = wg[(kc * 112 + kr) * 16 + j4];
      *(float4*)&ws[kr * 68 + j4 * 4] = v;
    }
    __syncthreads();
    // compute: thread (r,q) handles k in [q*28, q*28+28)
#pragma unroll 1
    for (int i4 = 0; i4 < 7; ++i4) {
      float4 in4 = *(const float4*)&xs[r * 116 + q * 28 + i4 * 4];
#pragma unroll
      for (int kk = 0; kk < 4; ++kk) {
        float in = (kk == 0) ? in4.x : (kk == 1) ? in4.y : (kk == 2) ? in4.z : in4.w;
        const float4* __restrict__ wr = (const float4*)&ws[(q * 28 + i4 * 4 + kk) * 68];
#pragma unroll
        for (int j4 = 0; j4 < 16; ++j4) {
          float4 w = wr[j4];
          acc[4 * j4 + 0] = fmaf(in, w.x, acc[4 * j4 + 0]);
          acc[4 * j4 + 1] = fmaf(in, w.y, acc[4 * j4 + 1]);
          acc[4 * j4 + 2] = fmaf(in, w.z, acc[4 * j4 + 2]);
          acc[4 * j4 + 3] = fmaf(in, w.w, acc[4 * j4 + 3]);
        }
      }
    }
  }

  // quad reduce (lanes 1,2 within quad)
#pragma unroll
  for (int j = 0; j < 64; ++j) {
    acc[j] += __shfl_xor(acc[j], 1, 64);
    acc[j] += __shfl_xor(acc[j], 2, 64);
  }

  // lane keeps 16 channels (exec-masked static extract; rule #20)
  float v[16];
  if (q == 0) {
#pragma unroll
    for (int j = 0; j < 16; ++j) v[j] = acc[j];
  } else if (q == 1) {
#pragma unroll
    for (int j = 0; j < 16; ++j) v[j] = acc[16 + j];
  } else if (q == 2) {
#pragma unroll
    for (int j = 0; j < 16; ++j) v[j] = acc[32 + j];
  } else {
#pragma unroll
    for (int j = 0; j < 16; ++j) v[j] = acc[48 + j];
  }
  const int c0 = q * 16;
#pragma unroll
  for (int j = 0; j < 16; ++j) v[j] += bin[c0 + j];

  float o[16];
#pragma unroll
  for (int gg = 0; gg < 2; ++gg) {
    float mu = 0.f;
#pragma unroll
    for (int i = 0; i < 8; ++i) mu += v[gg * 8 + i];
    mu *= 0.125f;
    float var = 0.f;
#pragma unroll
    for (int i = 0; i < 8; ++i) { float d = v[gg * 8 + i] - mu; var = fmaf(d, d, var); }
    var *= 0.125f;
    float rs = rsqrtf(var + EPS);
#pragma unroll
    for (int i = 0; i < 8; ++i) {
      float y = (v[gg * 8 + i] - mu) * rs * g1[c0 + gg * 8 + i] + be1[c0 + gg * 8 + i];
      o[gg * 8 + i] = tanh_fast(y);
    }
  }

  float4* dst = (float4*)(h0 + (row0 + r) * 64 + c0);
#pragma unroll
  for (int i = 0; i < 4; ++i)
    dst[i] = make_float4(o[4 * i], o[4 * i + 1], o[4 * i + 2], o[4 * i + 3]);
}

// ---------------------------------------------------------------------------
// Kernel B (MFMA split-bf16): RK4 + groupnorm2 + Wout + log_softmax.
// Swapped-operand GEMM: C'[ch][row] = W^T x u^T via mfma_f32_16x16x32_bf16.
//  - wave = 16 rows; block = 4 waves = 64 rows; grid 1024.
//  - W1/W2 hi/lo A-frags resident: 32 x short8 = 128 VGPR, built once.
//  - u round-trips through per-wave-private LDS (bf16 hi/lo arrays,
//    stride 72, XOR-swizzle ((c&7)<<3) on 8-elem blocks -> ~2-4-way banks).
//  - k-slot mapping sigma(g,e)=32ks+8g+e used consistently for A and B
//    (dot-order invariance makes the HW k-permutation irrelevant).
//  - C layout (m89-verified): ch = mt*16 + 4*(lane>>4) + reg, row = lane&15.
//  - 3-term split: err ~2^-17/matvec. 48 MFMA + ~230 VALU + 24 LDS per eval.
//  - VGPR audit (round-4 fix): gamma2/beta2 frags moved to EPILOGUE —
//    keeping them resident put peak at ~260 > the (256,2) cap of 256 and
//    risked scratch spill (round-1 failure mode). Peak now ~230.
// ---------------------------------------------------------------------------
__global__ __launch_bounds__(256, 2) void kB(
    const float* __restrict__ h0,
    const float* __restrict__ W1, const float* __restrict__ b1,
    const float* __restrict__ W2, const float* __restrict__ b2,
    const float* __restrict__ g2, const float* __restrict__ be2,
    const float* __restrict__ Wout, const float* __restrict__ bout,
    const int* __restrict__ nsp, float* __restrict__ out) {
  __shared__ __align__(16) unsigned short UH[4][16 * 72];
  __shared__ __align__(16) unsigned short UL[4][16 * 72];

  const int tid = threadIdx.x;
  const int wid = tid >> 6;
  const int lane = tid & 63;
  const int c = lane & 15, g = lane >> 4;
  const int rowbase = blockIdx.x * 64 + wid * 16;
  const size_t myrow = (size_t)rowbase + c;
  const int xsw = (c & 7) << 3;

  unsigned short* __restrict__ uh = &UH[wid][c * 72];
  unsigned short* __restrict__ ul = &UL[wid][c * 72];

  // ---- resident W fragments (hi/lo), built once ----
  short8 WF[2][4][2][2];  // [layer][mt][ks][hi/lo]
#pragma unroll
  for (int L = 0; L < 2; ++L) {
    const float* __restrict__ W = L ? W2 : W1;
#pragma unroll
    for (int mt = 0; mt < 4; ++mt)
#pragma unroll
      for (int ks = 0; ks < 2; ++ks) {
        short8 hi8, lo8;
#pragma unroll
        for (int e = 0; e < 8; ++e) {
          float w = W[(ks * 32 + 8 * g + e) * 64 + mt * 16 + c];
          unsigned hb, lb; split_bf16(w, hb, lb);
          hi8[e] = (short)(hb >> 16);
          lo8[e] = (short)(lb >> 16);
        }
        WF[L][mt][ks][0] = hi8;
        WF[L][mt][ks][1] = lo8;
      }
  }

  // ---- bias fragments (needed every eval; gamma/beta loaded in epilogue) ----
  f32x4 bf[2][4];
#pragma unroll
  for (int mt = 0; mt < 4; ++mt) {
    bf[0][mt] = *(const f32x4*)&b1[mt * 16 + 4 * g];
    bf[1][mt] = *(const f32x4*)&b2[mt * 16 + 4 * g];
  }

  // ---- load h in C'-layout ----
  f32x4 h4[4], s4[4];
#pragma unroll
  for (int mt = 0; mt < 4; ++mt)
    h4[mt] = *(const f32x4*)&h0[myrow * 64 + mt * 16 + 4 * g];

  const int ns = *nsp;
  const float dt  = 1.0f / (float)ns;
  const float dt6 = dt * (1.0f / 6.0f);
  const float dt3 = dt * (1.0f / 3.0f);
  const float dth = dt * 0.5f;

#define WSPLIT(MT, V)                                                        \
  {                                                                          \
    unsigned hb[4], lb[4];                                                   \
    _Pragma("unroll") for (int i = 0; i < 4; ++i)                            \
        split_bf16((V)[i], hb[i], lb[i]);                                    \
    uint2v hp, lp;                                                           \
    hp[0] = (hb[0] >> 16) | (hb[1] & 0xffff0000u);                           \
    hp[1] = (hb[2] >> 16) | (hb[3] & 0xffff0000u);                           \
    lp[0] = (lb[0] >> 16) | (lb[1] & 0xffff0000u);                           \
    lp[1] = (lb[2] >> 16) | (lb[3] & 0xffff0000u);                           \
    int O = (MT) * 16 + 4 * g;                                               \
    int so = ((O & ~7) ^ xsw) | (O & 7);                                     \
    *(uint2v*)&uh[so] = hp;                                                  \
    *(uint2v*)&ul[so] = lp;                                                  \
  }

#define DO_LAYER(L, ACC)                                                     \
  {                                                                          \
    _Pragma("unroll") for (int mt = 0; mt < 4; ++mt) ACC[mt] = bf[L][mt];    \
    _Pragma("unroll") for (int ks = 0; ks < 2; ++ks) {                       \
      int so = (32 * ks + 8 * g) ^ xsw;                                      \
      short8 bh = *(const short8*)&uh[so];                                   \
      short8 bl = *(const short8*)&ul[so];                                   \
      _Pragma("unroll") for (int mt = 0; mt < 4; ++mt) {                     \
        ACC[mt] = MF(WF[L][mt][ks][0], bh, ACC[mt]);                         \
        ACC[mt] = MF(WF[L][mt][ks][0], bl, ACC[mt]);                         \
        ACC[mt] = MF(WF[L][mt][ks][1], bh, ACC[mt]);                         \
      }                                                                      \
    }                                                                        \
  }

#pragma unroll 1
  for (int step = 0; step < ns; ++step) {
#pragma unroll
    for (int mt = 0; mt < 4; ++mt) {
      WSPLIT(mt, h4[mt]);
      s4[mt] = h4[mt];
    }
#pragma unroll 1
    for (int e = 0; e < 4; ++e) {
      f32x4 z[4];
      DO_LAYER(0, z);
#pragma unroll
      for (int mt = 0; mt < 4; ++mt) {
        f32x4 t;
        t[0] = tanh_fast(z[mt][0]); t[1] = tanh_fast(z[mt][1]);
        t[2] = tanh_fast(z[mt][2]); t[3] = tanh_fast(z[mt][3]);
        WSPLIT(mt, t);
      }
      f32x4 kv[4];
      DO_LAYER(1, kv);
      if (e < 3) {
        const float cs = (e == 0) ? dt6 : dt3;
        const float ca = (e == 2) ? dt : dth;
#pragma unroll
        for (int mt = 0; mt < 4; ++mt) {
          f32x4 a;
#pragma unroll
          for (int i = 0; i < 4; ++i) {
            s4[mt][i] = fmaf(cs, kv[mt][i], s4[mt][i]);
            a[i]      = fmaf(ca, kv[mt][i], h4[mt][i]);
          }
          WSPLIT(mt, a);
        }
      } else {
#pragma unroll
        for (int mt = 0; mt < 4; ++mt)
#pragma unroll
          for (int i = 0; i < 4; ++i)
            h4[mt][i] = fmaf(dt6, kv[mt][i], s4[mt][i]);
      }
    }
  }

  // ---- epilogue-only gamma/beta fragments (VGPR relief) ----
  f32x4 gf[4], bef[4];
#pragma unroll
  for (int mt = 0; mt < 4; ++mt) {
    gf[mt]  = *(const f32x4*)&g2[mt * 16 + 4 * g];
    bef[mt] = *(const f32x4*)&be2[mt * 16 + 4 * g];
  }

  // ---- groupnorm2: group of 8 ch = lane quad + partner lane (g^1 = l^16) ----
  f32x4 gn[4];
#pragma unroll
  for (int mt = 0; mt < 4; ++mt) {
    float sum = h4[mt][0] + h4[mt][1] + h4[mt][2] + h4[mt][3];
    sum += __shfl_xor(sum, 16, 64);
    float mu = sum * 0.125f;
    float vr = 0.f;
#pragma unroll
    for (int i = 0; i < 4; ++i) { float d = h4[mt][i] - mu; vr = fmaf(d, d, vr); }
    vr += __shfl_xor(vr, 16, 64);
    float rs = rsqrtf(vr * 0.125f + EPS);
#pragma unroll
    for (int i = 0; i < 4; ++i)
      gn[mt][i] = (h4[mt][i] - mu) * rs * gf[mt][i] + bef[mt][i];
  }

  // ---- logits: per-lane partial over its 16 ch, then xor16+xor32 reduce ----
  float lg[10];
#pragma unroll
  for (int cl = 0; cl < 10; ++cl) lg[cl] = 0.f;
#pragma unroll
  for (int mt = 0; mt < 4; ++mt)
#pragma unroll
    for (int rr = 0; rr < 4; ++rr) {
      int ch = mt * 16 + 4 * g + rr;
      float gv = gn[mt][rr];
      const float* __restrict__ wr = Wout + ch * 10;
#pragma unroll
      for (int cl = 0; cl < 10; ++cl) lg[cl] = fmaf(gv, wr[cl], lg[cl]);
    }
#pragma unroll
  for (int cl = 0; cl < 10; ++cl) {
    lg[cl] += __shfl_xor(lg[cl], 16, 64);
    lg[cl] += __shfl_xor(lg[cl], 32, 64);
    lg[cl] += bout[cl];
  }

  float m = lg[0];
#pragma unroll
  for (int cl = 1; cl < 10; ++cl) m = fmaxf(m, lg[cl]);
  float sum = 0.f;
#pragma unroll
  for (int cl = 0; cl < 10; ++cl) sum += __expf(lg[cl] - m);
  float lse = m + __logf(sum);

  if (g == 0) {
    float* op = out + myrow * 10;
#pragma unroll
    for (int cl = 0; cl < 10; ++cl) op[cl] = lg[cl] - lse;
  }
}

extern "C" void kernel_launch(void* const* d_in, const int* in_sizes, int n_in,
                              void* d_out, int out_size, void* d_ws, size_t ws_size,
                              hipStream_t stream) {
  const float* x    = (const float*)d_in[0];
  const float* Win  = (const float*)d_in[1];
  const float* bin  = (const float*)d_in[2];
  const float* g1   = (const float*)d_in[3];
  const float* be1  = (const float*)d_in[4];
  const float* W1   = (const float*)d_in[5];
  const float* b1   = (const float*)d_in[6];
  const float* W2   = (const float*)d_in[7];
  const float* b2   = (const float*)d_in[8];
  const float* g2   = (const float*)d_in[9];
  const float* be2  = (const float*)d_in[10];
  const float* Wout = (const float*)d_in[11];
  const float* bout = (const float*)d_in[12];
  const int*   nsp  = (const int*)d_in[13];
  float* out = (float*)d_out;
  float* h0  = (float*)d_ws;   // 65536*64*4 = 16.78 MB scratch

  kA<<<1024, 256, 0, stream>>>(x, Win, bin, g1, be1, h0);
  kB<<<1024, 256, 0, stream>>>(h0, W1, b1, W2, b2, g2, be2, Wout, bout, nsp, out);
}